// Round 7
// baseline (303.335 us; speedup 1.0000x reference)
//
#include <hip/hip_runtime.h>
#include <hip/hip_fp16.h>

#define NC_MEM 64
#define NC_IMG 64
#define NC     128
#define B_     32
#define H_     64
#define W_     96
#define HW_    (H_ * W_)      // 6144
#define P_TILE 64             // v7: half tile, 256-thread blocks
#define NTILES (HW_ / P_TILE) // 96
#define FS     520            // frag stride in ushorts: 512 + 8 pad
#define FOFF(pt, ks) ((((pt) * 4) + (ks)) * FS)
// rotated block placement, applied on every write and read (pure relabeling)
#define XOFF(pt, ks, blk) (FOFF(pt, ks) + ((((blk) + (pt)) & 63) << 3))

// d_ws byte layout
#define WA_HI  0                       // ushort[3][8][4][64][8] (f16 hi, A-frag order)
#define WA_LO  98304                   // f16 lo (w - f16(w))
#define XF_OFF 196608                  // float[32][16]
#define UM_OFF 198656                  // float[32]

typedef _Float16 f16x8 __attribute__((ext_vector_type(8)));
typedef __attribute__((ext_vector_type(4))) float f32x4;

__device__ inline unsigned pk2h(float a, float b) {
    __half2 h = __floats2half2_rn(a, b);
    return *(const unsigned*)&h;
}

// LDS-only barrier (orders ds ops without draining vmcnt); proven safe in v6.
__device__ inline void bar_lds() {
    __builtin_amdgcn_sched_barrier(0);
    asm volatile("s_waitcnt lgkmcnt(0)" ::: "memory");
    __builtin_amdgcn_s_barrier();
    asm volatile("" ::: "memory");
    __builtin_amdgcn_sched_barrier(0);
}

// ---------------------------------------------------------------------------
// prep: blocks 0..191 split W into f16 hi/lo in MFMA A-fragment order;
// block 192 computes xf via adjugate inverse + decodes use_memory.
// ---------------------------------------------------------------------------
__global__ void prep(const float* __restrict__ Ws,
                     const float* __restrict__ prev_ext,
                     const float* __restrict__ cur_ext,
                     const int* __restrict__ mem_idx,
                     const unsigned char* __restrict__ um_raw,
                     unsigned char* __restrict__ wsb) {
    if (blockIdx.x < 192) {
        int idx = blockIdx.x * 256 + threadIdx.x;   // < 49152 = 3*128*128
        int l = idx >> 14, r = idx & 16383, o = r >> 7, c = r & 127;
        float w = Ws[idx];
        __half hi = __float2half_rn(w);
        __half lo = __float2half_rn(w - __half2float(hi));
        int mt = o >> 4, lm = o & 15, ks = c >> 5, kr = c & 31, q = kr >> 3, j = kr & 7;
        int lane = q * 16 + lm;
        int di = ((((l * 8 + mt) * 4 + ks) * 64 + lane) << 3) + j;
        ((unsigned short*)(wsb + WA_HI))[di] = __half_as_ushort(hi);
        ((unsigned short*)(wsb + WA_LO))[di] = __half_as_ushort(lo);
        return;
    }
    int tb = threadIdx.x;
    if (tb >= 64) return;
    bool flag = (tb < 32) && (tb & 3) && (um_raw[tb] != 0);
    bool is_bool = __any(flag);
    if (tb >= B_) return;
    int b = tb;
    bool um = is_bool ? (um_raw[b] != 0) : (((const int*)um_raw)[b] != 0);
    int mi = mem_idx[b];

    float a[16];
#pragma unroll
    for (int i = 0; i < 16; ++i)
        a[i] = um ? prev_ext[mi * 16 + i] : ((i % 5 == 0) ? 1.f : 0.f);

    float s0 = a[0]*a[5]  - a[1]*a[4];
    float s1 = a[0]*a[6]  - a[2]*a[4];
    float s2 = a[0]*a[7]  - a[3]*a[4];
    float s3 = a[1]*a[6]  - a[2]*a[5];
    float s4 = a[1]*a[7]  - a[3]*a[5];
    float s5 = a[2]*a[7]  - a[3]*a[6];
    float c5 = a[10]*a[15] - a[11]*a[14];
    float c4 = a[9]*a[15]  - a[11]*a[13];
    float c3 = a[9]*a[14]  - a[10]*a[13];
    float c2 = a[8]*a[15]  - a[11]*a[12];
    float c1 = a[8]*a[14]  - a[10]*a[12];
    float c0 = a[8]*a[13]  - a[9]*a[12];
    float det = s0*c5 - s1*c4 + s2*c3 + s3*c2 - s4*c1 + s5*c0;
    float id = 1.0f / det;

    float inv[16];
    inv[0]  = ( a[5]*c5  - a[6]*c4  + a[7]*c3)  * id;
    inv[1]  = (-a[1]*c5  + a[2]*c4  - a[3]*c3)  * id;
    inv[2]  = ( a[13]*s5 - a[14]*s4 + a[15]*s3) * id;
    inv[3]  = (-a[9]*s5  + a[10]*s4 - a[11]*s3) * id;
    inv[4]  = (-a[4]*c5  + a[6]*c2  - a[7]*c1)  * id;
    inv[5]  = ( a[0]*c5  - a[2]*c2  + a[3]*c1)  * id;
    inv[6]  = (-a[12]*s5 + a[14]*s2 - a[15]*s1) * id;
    inv[7]  = ( a[8]*s5  - a[10]*s2 + a[11]*s1) * id;
    inv[8]  = ( a[4]*c4  - a[5]*c2  + a[7]*c0)  * id;
    inv[9]  = (-a[0]*c4  + a[1]*c2  - a[3]*c0)  * id;
    inv[10] = ( a[12]*s4 - a[13]*s2 + a[15]*s0) * id;
    inv[11] = (-a[8]*s4  + a[9]*s2  - a[11]*s0) * id;
    inv[12] = (-a[4]*c3  + a[5]*c1  - a[6]*c0)  * id;
    inv[13] = ( a[0]*c3  - a[1]*c1  + a[2]*c0)  * id;
    inv[14] = (-a[12]*s3 + a[13]*s1 - a[14]*s0) * id;
    inv[15] = ( a[8]*s3  - a[9]*s1  + a[10]*s0) * id;

    float* xf = (float*)(wsb + XF_OFF) + b * 16;
#pragma unroll
    for (int i = 0; i < 4; ++i)
#pragma unroll
        for (int j2 = 0; j2 < 4; ++j2) {
            float s = 0.f;
#pragma unroll
            for (int k = 0; k < 4; ++k)
                s += cur_ext[b * 16 + i * 4 + k] * inv[k * 4 + j2];
            xf[i * 4 + j2] = s;
        }
    ((float*)(wsb + UM_OFF))[b] = um ? 1.f : 0.f;
}

// ---------------------------------------------------------------------------
// fused_main v7: 256-thread (4-wave) blocks on 64-px tiles, grid 96x32=3072.
// Rationale: v1==v2==v4==v6 at 52-53 us despite every block-internal change
// (vectorized staging, prefetch, bank-conflict fixes, barrier count, LDS
// footprint 66->33KB, lgkm-only barriers) -- and OccupancyPercent pinned at
// ~32% (~1.3 resident 512-thread blocks/CU) in ALL of them. Pipe accounting
// (MFMA ~15.5us, LDS ~14us, VALU ~10us per CU) sums to the observed 52us,
// i.e. near-zero pipe overlap: in-block waves are barrier-lockstepped into
// the same phase, and cross-block phase diversity never materializes because
// residency never rises. v7 halves the scheduling quantum: 4-wave blocks,
// 16.6KB LDS -> up to 8 blocks/CU by every limit (waves/LDS/VGPR), 12-deep
// grid averages the umb work imbalance. Per-wave work and all verified
// staging/fragment/writeback formulas are IDENTICAL (og=t>>4 unchanged,
// q=t&15, pt 0..3, nt spans all 4 row-tiles of the 64-px tile).
// ---------------------------------------------------------------------------
__global__ __launch_bounds__(256, 8)
void fused_main(const float* __restrict__ img, const float* __restrict__ mem,
                const int* __restrict__ mem_idx, const float* __restrict__ bs,
                const unsigned char* __restrict__ wsb, float* __restrict__ out) {
    __shared__ unsigned short xh[16 * FS]; // 16640 B -> 8 blocks/CU

    const int t   = threadIdx.x;
    const int b   = blockIdx.y;
    const int hw0 = blockIdx.x * P_TILE;
    const bool umb = ((const float*)(wsb + UM_OFF))[b] != 0.f;
    const int mi  = mem_idx[b];

    const f16x8* __restrict__ WH = (const f16x8*)(wsb + WA_HI);
    const f16x8* __restrict__ WL = (const f16x8*)(wsb + WA_LO);

    const int w    = t >> 6;        // 0..3
    const int lane = t & 63;
    const int wq   = lane >> 4;
    const int lm   = lane & 15;
    const int mt0  = 2 * w;         // wave's mt pair: 0,2,4,6
    const int mt2  = 4 + w;         // wave's L2 mt: 4..7

#define FI(l, mt, ks) (((((l) * 8 + (mt)) * 4) + (ks)) * 64 + lane)

    // ---- stage: global f32 -> (FTL) -> f16 in LDS, rotated frag order ----
    {
        const int q   = t & 15;        // px quad: px = 4q..4q+3 (0..63)
        const int og  = t >> 4;        // channel octet 0..15
        const int px0 = hw0 + q * 4;
        const int pt  = q >> 2;        // 0..3
        if (umb) {
            const int c0 = og * 8;     // 8 channels, one side of 64
            const float* basep = (c0 < NC_MEM)
                ? (mem + ((size_t)mi * NC_MEM + c0) * HW_ + px0)
                : (img + ((size_t)b * NC_IMG + (c0 - NC_MEM)) * HW_ + px0);
            f32x4 v[8];
#pragma unroll
            for (int cc = 0; cc < 8; ++cc)
                v[cc] = *(const f32x4*)(basep + (size_t)cc * HW_);
            if (og < 4) {              // FTL on channel groups 0..7 (c < 32)
                float xfv[16];
                const float* xfp = (const float*)(wsb + XF_OFF) + b * 16;
#pragma unroll
                for (int j = 0; j < 4; ++j)
                    *(f32x4*)&xfv[j * 4] = *(const f32x4*)&xfp[j * 4];
#pragma unroll
                for (int sg = 0; sg < 2; ++sg) {
#pragma unroll
                    for (int i = 0; i < 4; ++i) {
                        float a0 = v[4*sg+0][i], a1 = v[4*sg+1][i];
                        float a2 = v[4*sg+2][i], a3 = v[4*sg+3][i];
                        v[4*sg+0][i] = xfv[0]*a0  + xfv[1]*a1  + xfv[2]*a2  + xfv[3]*a3;
                        v[4*sg+1][i] = xfv[4]*a0  + xfv[5]*a1  + xfv[6]*a2  + xfv[7]*a3;
                        v[4*sg+2][i] = xfv[8]*a0  + xfv[9]*a1  + xfv[10]*a2 + xfv[11]*a3;
                        v[4*sg+3][i] = xfv[12]*a0 + xfv[13]*a1 + xfv[14]*a2 + xfv[15]*a3;
                    }
                }
            }
            const int bk0 = (og & 3) * 16 + (q & 3) * 4;
#pragma unroll
            for (int i = 0; i < 4; ++i) {
                uint4 pk;
                pk.x = pk2h(v[0][i], v[1][i]);
                pk.y = pk2h(v[2][i], v[3][i]);
                pk.z = pk2h(v[4][i], v[5][i]);
                pk.w = pk2h(v[6][i], v[7][i]);
                *(uint4*)&xh[XOFF(pt, og >> 2, bk0 + i)] = pk;
            }
        } else {
            // img channels only (groups 16..31); mem rows never read in L0
            const int gg = 16 + og;
            const int c0 = gg * 4 - NC_MEM;  // img channel 0..60
            f32x4 u[4];
#pragma unroll
            for (int cc = 0; cc < 4; ++cc)
                u[cc] = *(const f32x4*)(img + ((size_t)b * NC_IMG + c0 + cc) * HW_ + px0);
            const int bk0 = ((gg & 7) >> 1) * 16 + (q & 3) * 4;
            const int hoff = (gg & 1) * 4;
#pragma unroll
            for (int i = 0; i < 4; ++i)
                *(uint2*)&xh[XOFF(pt, gg >> 3, bk0 + i) + hoff] =
                    make_uint2(pk2h(u[0][i], u[1][i]), pk2h(u[2][i], u[3][i]));
        }
    }

    // ---- B-fragment read pointers: computed once, valid for all layers ----
    const unsigned short* bp[4];
#pragma unroll
    for (int nt = 0; nt < 4; ++nt)
        bp[nt] = &xh[XOFF(nt, 0, lane)];

    // ---- prefetch layer-0 A frags before the barrier ----
    const int kpa = umb ? 0 : 2, kpb = umb ? 1 : 3;
    f16x8 p0h = WH[FI(0, mt0,     kpa)], p0l = WL[FI(0, mt0,     kpa)];
    f16x8 p1h = WH[FI(0, mt0 + 1, kpa)], p1l = WL[FI(0, mt0 + 1, kpa)];
    f16x8 p2h = WH[FI(0, mt0,     kpb)], p2l = WL[FI(0, mt0,     kpb)];
    f16x8 p3h = WH[FI(0, mt0 + 1, kpb)], p3l = WL[FI(0, mt0 + 1, kpb)];

    bar_lds();   // B1: stage complete

    f32x4 acc[2][4];

    auto run_ks = [&](int ks, f16x8 ah0, f16x8 al0, f16x8 ah1, f16x8 al1) {
#pragma unroll
        for (int nt = 0; nt < 4; ++nt) {
            f16x8 bh = *(const f16x8*)(bp[nt] + ks * FS);
            acc[0][nt] = __builtin_amdgcn_mfma_f32_16x16x32_f16(ah0, bh, acc[0][nt], 0, 0, 0);
            acc[1][nt] = __builtin_amdgcn_mfma_f32_16x16x32_f16(ah1, bh, acc[1][nt], 0, 0, 0);
            acc[0][nt] = __builtin_amdgcn_mfma_f32_16x16x32_f16(al0, bh, acc[0][nt], 0, 0, 0);
            acc[1][nt] = __builtin_amdgcn_mfma_f32_16x16x32_f16(al1, bh, acc[1][nt], 0, 0, 0);
        }
    };
    auto writeback = [&]() {
#pragma unroll
        for (int mi2 = 0; mi2 < 2; ++mi2) {
            const int mt = mt0 + mi2;
            const int ks2 = mt >> 1;
            const int lane_f = ((mt & 1) * 2 + (wq >> 1)) * 16 + lm;
            const int j0 = (wq & 1) * 4;
#pragma unroll
            for (int nt = 0; nt < 4; ++nt) {
                float v0 = fmaxf(acc[mi2][nt][0], 0.f);
                float v1 = fmaxf(acc[mi2][nt][1], 0.f);
                float v2 = fmaxf(acc[mi2][nt][2], 0.f);
                float v3 = fmaxf(acc[mi2][nt][3], 0.f);
                *(uint2*)&xh[XOFF(nt, ks2, lane_f) + j0] =
                    make_uint2(pk2h(v0, v1), pk2h(v2, v3));
            }
        }
    };

    // ---------------- layer 0 ----------------
#pragma unroll
    for (int mi2 = 0; mi2 < 2; ++mi2) {
        f32x4 bv = *(const f32x4*)&bs[0 * NC + (mt0 + mi2) * 16 + wq * 4];
#pragma unroll
        for (int nt = 0; nt < 4; ++nt) acc[mi2][nt] = bv;
    }
    __builtin_amdgcn_s_setprio(1);
    if (umb) {
        run_ks(0, p0h, p0l, p1h, p1l);
        run_ks(1, p2h, p2l, p3h, p3l);
        run_ks(2, WH[FI(0, mt0, 2)], WL[FI(0, mt0, 2)],
                  WH[FI(0, mt0 + 1, 2)], WL[FI(0, mt0 + 1, 2)]);
        run_ks(3, WH[FI(0, mt0, 3)], WL[FI(0, mt0, 3)],
                  WH[FI(0, mt0 + 1, 3)], WL[FI(0, mt0 + 1, 3)]);
    } else {
        run_ks(2, p0h, p0l, p1h, p1l);
        run_ks(3, p2h, p2l, p3h, p3l);
    }
    __builtin_amdgcn_s_setprio(0);
    // prefetch layer-1 ks0/ks1 across the barriers
    f16x8 q0h = WH[FI(1, mt0, 0)],     q0l = WL[FI(1, mt0, 0)];
    f16x8 q1h = WH[FI(1, mt0 + 1, 0)], q1l = WL[FI(1, mt0 + 1, 0)];
    f16x8 q2h = WH[FI(1, mt0, 1)],     q2l = WL[FI(1, mt0, 1)];
    f16x8 q3h = WH[FI(1, mt0 + 1, 1)], q3l = WL[FI(1, mt0 + 1, 1)];
    bar_lds();              // B2: all layer-0 reads of xh done
    writeback();            // overwrite xh in place
    bar_lds();              // B3: layer-0 output visible

    // ---------------- layer 1 ----------------
#pragma unroll
    for (int mi2 = 0; mi2 < 2; ++mi2) {
        f32x4 bv = *(const f32x4*)&bs[1 * NC + (mt0 + mi2) * 16 + wq * 4];
#pragma unroll
        for (int nt = 0; nt < 4; ++nt) acc[mi2][nt] = bv;
    }
    __builtin_amdgcn_s_setprio(1);
    run_ks(0, q0h, q0l, q1h, q1l);
    run_ks(1, q2h, q2l, q3h, q3l);
    run_ks(2, WH[FI(1, mt0, 2)], WL[FI(1, mt0, 2)],
              WH[FI(1, mt0 + 1, 2)], WL[FI(1, mt0 + 1, 2)]);
    run_ks(3, WH[FI(1, mt0, 3)], WL[FI(1, mt0, 3)],
              WH[FI(1, mt0 + 1, 3)], WL[FI(1, mt0 + 1, 3)]);
    __builtin_amdgcn_s_setprio(0);
    // prefetch ALL layer-2 A frags (single mt per wave -> 8 frags)
    f16x8 r0h = WH[FI(2, mt2, 0)], r0l = WL[FI(2, mt2, 0)];
    f16x8 r1h = WH[FI(2, mt2, 1)], r1l = WL[FI(2, mt2, 1)];
    f16x8 r2h = WH[FI(2, mt2, 2)], r2l = WL[FI(2, mt2, 2)];
    f16x8 r3h = WH[FI(2, mt2, 3)], r3l = WL[FI(2, mt2, 3)];
    bar_lds();              // B4: all layer-1 reads of xh done
    writeback();
    bar_lds();              // B5: layer-1 output visible

    // ---------------- layer 2: out channels 64..127 only ----------------
    {
        f32x4 a2[4];
        f32x4 bv = *(const f32x4*)&bs[2 * NC + mt2 * 16 + wq * 4];
#pragma unroll
        for (int nt = 0; nt < 4; ++nt) a2[nt] = bv;
        auto run2 = [&](int ks, f16x8 ah, f16x8 al) {
#pragma unroll
            for (int nt = 0; nt < 4; ++nt) {
                f16x8 bh = *(const f16x8*)(bp[nt] + ks * FS);
                a2[nt] = __builtin_amdgcn_mfma_f32_16x16x32_f16(ah, bh, a2[nt], 0, 0, 0);
                a2[nt] = __builtin_amdgcn_mfma_f32_16x16x32_f16(al, bh, a2[nt], 0, 0, 0);
            }
        };
        __builtin_amdgcn_s_setprio(1);
        run2(0, r0h, r0l);
        run2(1, r1h, r1l);
        run2(2, r2h, r2l);
        run2(3, r3h, r3l);
        __builtin_amdgcn_s_setprio(0);
        const int oc0 = mt2 * 16 + wq * 4 - 64; // 0..60
#pragma unroll
        for (int nt = 0; nt < 4; ++nt) {
            float* dst = out + ((size_t)b * 64 + oc0) * HW_ + hw0 + nt * 16 + lm;
#pragma unroll
            for (int r = 0; r < 4; ++r)
                __builtin_nontemporal_store(a2[nt][r], dst + (size_t)r * HW_);
        }
    }
#undef FI
}

extern "C" void kernel_launch(void* const* d_in, const int* in_sizes, int n_in,
                              void* d_out, int out_size, void* d_ws, size_t ws_size,
                              hipStream_t stream) {
    const float* img  = (const float*)d_in[0];
    const float* mem  = (const float*)d_in[1];
    const float* pext = (const float*)d_in[2];
    const float* cext = (const float*)d_in[3];
    const int*   midx = (const int*)d_in[4];
    const unsigned char* umem = (const unsigned char*)d_in[5];
    const float* Ws   = (const float*)d_in[6];
    const float* bs   = (const float*)d_in[7];
    float* out = (float*)d_out;
    unsigned char* wsb = (unsigned char*)d_ws;

    hipLaunchKernelGGL(prep, dim3(193), dim3(256), 0, stream,
                       Ws, pext, cext, midx, umem, wsb);
    hipLaunchKernelGGL(fused_main, dim3(NTILES, B_), dim3(256), 0, stream,
                       img, mem, midx, bs, wsb, out);
}

// Round 8
// 160.653 us; speedup vs baseline: 1.8881x; 1.8881x over previous
//
#include <hip/hip_runtime.h>
#include <hip/hip_fp16.h>

#define NC_MEM 64
#define NC_IMG 64
#define NC     128
#define B_     32
#define H_     64
#define W_     96
#define HW_    (H_ * W_)      // 6144
#define P_TILE 64             // 64-px tiles, 256-thread blocks
#define NTILES (HW_ / P_TILE) // 96
#define FS     520            // frag stride in ushorts: 512 + 8 pad
#define FOFF(pt, ks) ((((pt) * 4) + (ks)) * FS)
// rotated block placement, applied on every write and read (pure relabeling)
#define XOFF(pt, ks, blk) (FOFF(pt, ks) + ((((blk) + (pt)) & 63) << 3))

// d_ws byte layout
#define WA_HI  0                       // ushort[3][8][4][64][8] (f16 hi, A-frag order)
#define WA_LO  98304                   // f16 lo (w - f16(w))
#define XF_OFF 196608                  // float[32][16]
#define UM_OFF 198656                  // float[32]

typedef _Float16 f16x8 __attribute__((ext_vector_type(8)));
typedef __attribute__((ext_vector_type(4))) float f32x4;

__device__ inline unsigned pk2h(float a, float b) {
    __half2 h = __floats2half2_rn(a, b);
    return *(const unsigned*)&h;
}

// LDS-only barrier (orders ds ops without draining vmcnt); proven safe in v6.
__device__ inline void bar_lds() {
    __builtin_amdgcn_sched_barrier(0);
    asm volatile("s_waitcnt lgkmcnt(0)" ::: "memory");
    __builtin_amdgcn_s_barrier();
    asm volatile("" ::: "memory");
    __builtin_amdgcn_sched_barrier(0);
}

// ---------------------------------------------------------------------------
// prep: blocks 0..191 split W into f16 hi/lo in MFMA A-fragment order;
// block 192 computes xf via adjugate inverse + decodes use_memory.
// ---------------------------------------------------------------------------
__global__ void prep(const float* __restrict__ Ws,
                     const float* __restrict__ prev_ext,
                     const float* __restrict__ cur_ext,
                     const int* __restrict__ mem_idx,
                     const unsigned char* __restrict__ um_raw,
                     unsigned char* __restrict__ wsb) {
    if (blockIdx.x < 192) {
        int idx = blockIdx.x * 256 + threadIdx.x;   // < 49152 = 3*128*128
        int l = idx >> 14, r = idx & 16383, o = r >> 7, c = r & 127;
        float w = Ws[idx];
        __half hi = __float2half_rn(w);
        __half lo = __float2half_rn(w - __half2float(hi));
        int mt = o >> 4, lm = o & 15, ks = c >> 5, kr = c & 31, q = kr >> 3, j = kr & 7;
        int lane = q * 16 + lm;
        int di = ((((l * 8 + mt) * 4 + ks) * 64 + lane) << 3) + j;
        ((unsigned short*)(wsb + WA_HI))[di] = __half_as_ushort(hi);
        ((unsigned short*)(wsb + WA_LO))[di] = __half_as_ushort(lo);
        return;
    }
    int tb = threadIdx.x;
    if (tb >= 64) return;
    bool flag = (tb < 32) && (tb & 3) && (um_raw[tb] != 0);
    bool is_bool = __any(flag);
    if (tb >= B_) return;
    int b = tb;
    bool um = is_bool ? (um_raw[b] != 0) : (((const int*)um_raw)[b] != 0);
    int mi = mem_idx[b];

    float a[16];
#pragma unroll
    for (int i = 0; i < 16; ++i)
        a[i] = um ? prev_ext[mi * 16 + i] : ((i % 5 == 0) ? 1.f : 0.f);

    float s0 = a[0]*a[5]  - a[1]*a[4];
    float s1 = a[0]*a[6]  - a[2]*a[4];
    float s2 = a[0]*a[7]  - a[3]*a[4];
    float s3 = a[1]*a[6]  - a[2]*a[5];
    float s4 = a[1]*a[7]  - a[3]*a[5];
    float s5 = a[2]*a[7]  - a[3]*a[6];
    float c5 = a[10]*a[15] - a[11]*a[14];
    float c4 = a[9]*a[15]  - a[11]*a[13];
    float c3 = a[9]*a[14]  - a[10]*a[13];
    float c2 = a[8]*a[15]  - a[11]*a[12];
    float c1 = a[8]*a[14]  - a[10]*a[12];
    float c0 = a[8]*a[13]  - a[9]*a[12];
    float det = s0*c5 - s1*c4 + s2*c3 + s3*c2 - s4*c1 + s5*c0;
    float id = 1.0f / det;

    float inv[16];
    inv[0]  = ( a[5]*c5  - a[6]*c4  + a[7]*c3)  * id;
    inv[1]  = (-a[1]*c5  + a[2]*c4  - a[3]*c3)  * id;
    inv[2]  = ( a[13]*s5 - a[14]*s4 + a[15]*s3) * id;
    inv[3]  = (-a[9]*s5  + a[10]*s4 - a[11]*s3) * id;
    inv[4]  = (-a[4]*c5  + a[6]*c2  - a[7]*c1)  * id;
    inv[5]  = ( a[0]*c5  - a[2]*c2  + a[3]*c1)  * id;
    inv[6]  = (-a[12]*s5 + a[14]*s2 - a[15]*s1) * id;
    inv[7]  = ( a[8]*s5  - a[10]*s2 + a[11]*s1) * id;
    inv[8]  = ( a[4]*c4  - a[5]*c2  + a[7]*c0)  * id;
    inv[9]  = (-a[0]*c4  + a[1]*c2  - a[3]*c0)  * id;
    inv[10] = ( a[12]*s4 - a[13]*s2 + a[15]*s0) * id;
    inv[11] = (-a[8]*s4  + a[9]*s2  - a[11]*s0) * id;
    inv[12] = (-a[4]*c3  + a[5]*c1  - a[6]*c0)  * id;
    inv[13] = ( a[0]*c3  - a[1]*c1  + a[2]*c0)  * id;
    inv[14] = (-a[12]*s3 + a[13]*s1 - a[14]*s0) * id;
    inv[15] = ( a[8]*s3  - a[9]*s1  + a[10]*s0) * id;

    float* xf = (float*)(wsb + XF_OFF) + b * 16;
#pragma unroll
    for (int i = 0; i < 4; ++i)
#pragma unroll
        for (int j2 = 0; j2 < 4; ++j2) {
            float s = 0.f;
#pragma unroll
            for (int k = 0; k < 4; ++k)
                s += cur_ext[b * 16 + i * 4 + k] * inv[k * 4 + j2];
            xf[i * 4 + j2] = s;
        }
    ((float*)(wsb + UM_OFF))[b] = um ? 1.f : 0.f;
}

// ---------------------------------------------------------------------------
// fused_main v8 = v7 structure with __launch_bounds__(256, 4).
// v7's (256,8) repeated v3's register-cap mistake: min 8 waves/SIMD -> 64
// unified regs/wave -> 32 arch VGPR -> ~500 MB scratch spill, 200 us. BUT it
// also demonstrated the occupancy mechanism works: 73% resident (vs 32% for
// every 512-thread variant). v8 keeps the 4-wave block / 16.6 KB LDS / 3072-
// block grid and restores the 128-reg cap (natural 64-VGPR alloc, proven in
// v2/v4/v6 with identical per-wave live state). Limits then coincide at
// 8 blocks/CU: waves (32/4), LDS (160/16.6), VGPR (64-reg -> 8 waves/SIMD).
// Per-wave work and all verified staging/fragment/writeback formulas are
// IDENTICAL to v6 (og=t>>4; q=t&15; pt 0..3; nt spans the 4 row-tiles).
// ---------------------------------------------------------------------------
__global__ __launch_bounds__(256, 4)
void fused_main(const float* __restrict__ img, const float* __restrict__ mem,
                const int* __restrict__ mem_idx, const float* __restrict__ bs,
                const unsigned char* __restrict__ wsb, float* __restrict__ out) {
    __shared__ unsigned short xh[16 * FS]; // 16640 B

    const int t   = threadIdx.x;
    const int b   = blockIdx.y;
    const int hw0 = blockIdx.x * P_TILE;
    const bool umb = ((const float*)(wsb + UM_OFF))[b] != 0.f;
    const int mi  = mem_idx[b];

    const f16x8* __restrict__ WH = (const f16x8*)(wsb + WA_HI);
    const f16x8* __restrict__ WL = (const f16x8*)(wsb + WA_LO);

    const int w    = t >> 6;        // 0..3
    const int lane = t & 63;
    const int wq   = lane >> 4;
    const int lm   = lane & 15;
    const int mt0  = 2 * w;         // wave's mt pair: 0,2,4,6
    const int mt2  = 4 + w;         // wave's L2 mt: 4..7

#define FI(l, mt, ks) (((((l) * 8 + (mt)) * 4) + (ks)) * 64 + lane)

    // ---- stage: global f32 -> (FTL) -> f16 in LDS, rotated frag order ----
    {
        const int q   = t & 15;        // px quad: px = 4q..4q+3 (0..63)
        const int og  = t >> 4;        // channel octet 0..15
        const int px0 = hw0 + q * 4;
        const int pt  = q >> 2;        // 0..3
        if (umb) {
            const int c0 = og * 8;     // 8 channels, one side of 64
            const float* basep = (c0 < NC_MEM)
                ? (mem + ((size_t)mi * NC_MEM + c0) * HW_ + px0)
                : (img + ((size_t)b * NC_IMG + (c0 - NC_MEM)) * HW_ + px0);
            f32x4 v[8];
#pragma unroll
            for (int cc = 0; cc < 8; ++cc)
                v[cc] = *(const f32x4*)(basep + (size_t)cc * HW_);
            if (og < 4) {              // FTL on channel groups 0..7 (c < 32)
                float xfv[16];
                const float* xfp = (const float*)(wsb + XF_OFF) + b * 16;
#pragma unroll
                for (int j = 0; j < 4; ++j)
                    *(f32x4*)&xfv[j * 4] = *(const f32x4*)&xfp[j * 4];
#pragma unroll
                for (int sg = 0; sg < 2; ++sg) {
#pragma unroll
                    for (int i = 0; i < 4; ++i) {
                        float a0 = v[4*sg+0][i], a1 = v[4*sg+1][i];
                        float a2 = v[4*sg+2][i], a3 = v[4*sg+3][i];
                        v[4*sg+0][i] = xfv[0]*a0  + xfv[1]*a1  + xfv[2]*a2  + xfv[3]*a3;
                        v[4*sg+1][i] = xfv[4]*a0  + xfv[5]*a1  + xfv[6]*a2  + xfv[7]*a3;
                        v[4*sg+2][i] = xfv[8]*a0  + xfv[9]*a1  + xfv[10]*a2 + xfv[11]*a3;
                        v[4*sg+3][i] = xfv[12]*a0 + xfv[13]*a1 + xfv[14]*a2 + xfv[15]*a3;
                    }
                }
            }
            const int bk0 = (og & 3) * 16 + (q & 3) * 4;
#pragma unroll
            for (int i = 0; i < 4; ++i) {
                uint4 pk;
                pk.x = pk2h(v[0][i], v[1][i]);
                pk.y = pk2h(v[2][i], v[3][i]);
                pk.z = pk2h(v[4][i], v[5][i]);
                pk.w = pk2h(v[6][i], v[7][i]);
                *(uint4*)&xh[XOFF(pt, og >> 2, bk0 + i)] = pk;
            }
        } else {
            // img channels only (groups 16..31); mem rows never read in L0
            const int gg = 16 + og;
            const int c0 = gg * 4 - NC_MEM;  // img channel 0..60
            f32x4 u[4];
#pragma unroll
            for (int cc = 0; cc < 4; ++cc)
                u[cc] = *(const f32x4*)(img + ((size_t)b * NC_IMG + c0 + cc) * HW_ + px0);
            const int bk0 = ((gg & 7) >> 1) * 16 + (q & 3) * 4;
            const int hoff = (gg & 1) * 4;
#pragma unroll
            for (int i = 0; i < 4; ++i)
                *(uint2*)&xh[XOFF(pt, gg >> 3, bk0 + i) + hoff] =
                    make_uint2(pk2h(u[0][i], u[1][i]), pk2h(u[2][i], u[3][i]));
        }
    }

    // ---- B-fragment read pointers: computed once, valid for all layers ----
    const unsigned short* bp[4];
#pragma unroll
    for (int nt = 0; nt < 4; ++nt)
        bp[nt] = &xh[XOFF(nt, 0, lane)];

    // ---- prefetch layer-0 A frags before the barrier ----
    const int kpa = umb ? 0 : 2, kpb = umb ? 1 : 3;
    f16x8 p0h = WH[FI(0, mt0,     kpa)], p0l = WL[FI(0, mt0,     kpa)];
    f16x8 p1h = WH[FI(0, mt0 + 1, kpa)], p1l = WL[FI(0, mt0 + 1, kpa)];
    f16x8 p2h = WH[FI(0, mt0,     kpb)], p2l = WL[FI(0, mt0,     kpb)];
    f16x8 p3h = WH[FI(0, mt0 + 1, kpb)], p3l = WL[FI(0, mt0 + 1, kpb)];

    bar_lds();   // B1: stage complete

    f32x4 acc[2][4];

    auto run_ks = [&](int ks, f16x8 ah0, f16x8 al0, f16x8 ah1, f16x8 al1) {
#pragma unroll
        for (int nt = 0; nt < 4; ++nt) {
            f16x8 bh = *(const f16x8*)(bp[nt] + ks * FS);
            acc[0][nt] = __builtin_amdgcn_mfma_f32_16x16x32_f16(ah0, bh, acc[0][nt], 0, 0, 0);
            acc[1][nt] = __builtin_amdgcn_mfma_f32_16x16x32_f16(ah1, bh, acc[1][nt], 0, 0, 0);
            acc[0][nt] = __builtin_amdgcn_mfma_f32_16x16x32_f16(al0, bh, acc[0][nt], 0, 0, 0);
            acc[1][nt] = __builtin_amdgcn_mfma_f32_16x16x32_f16(al1, bh, acc[1][nt], 0, 0, 0);
        }
    };
    auto writeback = [&]() {
#pragma unroll
        for (int mi2 = 0; mi2 < 2; ++mi2) {
            const int mt = mt0 + mi2;
            const int ks2 = mt >> 1;
            const int lane_f = ((mt & 1) * 2 + (wq >> 1)) * 16 + lm;
            const int j0 = (wq & 1) * 4;
#pragma unroll
            for (int nt = 0; nt < 4; ++nt) {
                float v0 = fmaxf(acc[mi2][nt][0], 0.f);
                float v1 = fmaxf(acc[mi2][nt][1], 0.f);
                float v2 = fmaxf(acc[mi2][nt][2], 0.f);
                float v3 = fmaxf(acc[mi2][nt][3], 0.f);
                *(uint2*)&xh[XOFF(nt, ks2, lane_f) + j0] =
                    make_uint2(pk2h(v0, v1), pk2h(v2, v3));
            }
        }
    };

    // ---------------- layer 0 ----------------
#pragma unroll
    for (int mi2 = 0; mi2 < 2; ++mi2) {
        f32x4 bv = *(const f32x4*)&bs[0 * NC + (mt0 + mi2) * 16 + wq * 4];
#pragma unroll
        for (int nt = 0; nt < 4; ++nt) acc[mi2][nt] = bv;
    }
    __builtin_amdgcn_s_setprio(1);
    if (umb) {
        run_ks(0, p0h, p0l, p1h, p1l);
        run_ks(1, p2h, p2l, p3h, p3l);
        run_ks(2, WH[FI(0, mt0, 2)], WL[FI(0, mt0, 2)],
                  WH[FI(0, mt0 + 1, 2)], WL[FI(0, mt0 + 1, 2)]);
        run_ks(3, WH[FI(0, mt0, 3)], WL[FI(0, mt0, 3)],
                  WH[FI(0, mt0 + 1, 3)], WL[FI(0, mt0 + 1, 3)]);
    } else {
        run_ks(2, p0h, p0l, p1h, p1l);
        run_ks(3, p2h, p2l, p3h, p3l);
    }
    __builtin_amdgcn_s_setprio(0);
    // prefetch layer-1 ks0/ks1 across the barriers
    f16x8 q0h = WH[FI(1, mt0, 0)],     q0l = WL[FI(1, mt0, 0)];
    f16x8 q1h = WH[FI(1, mt0 + 1, 0)], q1l = WL[FI(1, mt0 + 1, 0)];
    f16x8 q2h = WH[FI(1, mt0, 1)],     q2l = WL[FI(1, mt0, 1)];
    f16x8 q3h = WH[FI(1, mt0 + 1, 1)], q3l = WL[FI(1, mt0 + 1, 1)];
    bar_lds();              // B2: all layer-0 reads of xh done
    writeback();            // overwrite xh in place
    bar_lds();              // B3: layer-0 output visible

    // ---------------- layer 1 ----------------
#pragma unroll
    for (int mi2 = 0; mi2 < 2; ++mi2) {
        f32x4 bv = *(const f32x4*)&bs[1 * NC + (mt0 + mi2) * 16 + wq * 4];
#pragma unroll
        for (int nt = 0; nt < 4; ++nt) acc[mi2][nt] = bv;
    }
    __builtin_amdgcn_s_setprio(1);
    run_ks(0, q0h, q0l, q1h, q1l);
    run_ks(1, q2h, q2l, q3h, q3l);
    run_ks(2, WH[FI(1, mt0, 2)], WL[FI(1, mt0, 2)],
              WH[FI(1, mt0 + 1, 2)], WL[FI(1, mt0 + 1, 2)]);
    run_ks(3, WH[FI(1, mt0, 3)], WL[FI(1, mt0, 3)],
              WH[FI(1, mt0 + 1, 3)], WL[FI(1, mt0 + 1, 3)]);
    __builtin_amdgcn_s_setprio(0);
    // prefetch ALL layer-2 A frags (single mt per wave -> 8 frags)
    f16x8 r0h = WH[FI(2, mt2, 0)], r0l = WL[FI(2, mt2, 0)];
    f16x8 r1h = WH[FI(2, mt2, 1)], r1l = WL[FI(2, mt2, 1)];
    f16x8 r2h = WH[FI(2, mt2, 2)], r2l = WL[FI(2, mt2, 2)];
    f16x8 r3h = WH[FI(2, mt2, 3)], r3l = WL[FI(2, mt2, 3)];
    bar_lds();              // B4: all layer-1 reads of xh done
    writeback();
    bar_lds();              // B5: layer-1 output visible

    // ---------------- layer 2: out channels 64..127 only ----------------
    {
        f32x4 a2[4];
        f32x4 bv = *(const f32x4*)&bs[2 * NC + mt2 * 16 + wq * 4];
#pragma unroll
        for (int nt = 0; nt < 4; ++nt) a2[nt] = bv;
        auto run2 = [&](int ks, f16x8 ah, f16x8 al) {
#pragma unroll
            for (int nt = 0; nt < 4; ++nt) {
                f16x8 bh = *(const f16x8*)(bp[nt] + ks * FS);
                a2[nt] = __builtin_amdgcn_mfma_f32_16x16x32_f16(ah, bh, a2[nt], 0, 0, 0);
                a2[nt] = __builtin_amdgcn_mfma_f32_16x16x32_f16(al, bh, a2[nt], 0, 0, 0);
            }
        };
        __builtin_amdgcn_s_setprio(1);
        run2(0, r0h, r0l);
        run2(1, r1h, r1l);
        run2(2, r2h, r2l);
        run2(3, r3h, r3l);
        __builtin_amdgcn_s_setprio(0);
        const int oc0 = mt2 * 16 + wq * 4 - 64; // 0..60
#pragma unroll
        for (int nt = 0; nt < 4; ++nt) {
            float* dst = out + ((size_t)b * 64 + oc0) * HW_ + hw0 + nt * 16 + lm;
#pragma unroll
            for (int r = 0; r < 4; ++r)
                __builtin_nontemporal_store(a2[nt][r], dst + (size_t)r * HW_);
        }
    }
#undef FI
}

extern "C" void kernel_launch(void* const* d_in, const int* in_sizes, int n_in,
                              void* d_out, int out_size, void* d_ws, size_t ws_size,
                              hipStream_t stream) {
    const float* img  = (const float*)d_in[0];
    const float* mem  = (const float*)d_in[1];
    const float* pext = (const float*)d_in[2];
    const float* cext = (const float*)d_in[3];
    const int*   midx = (const int*)d_in[4];
    const unsigned char* umem = (const unsigned char*)d_in[5];
    const float* Ws   = (const float*)d_in[6];
    const float* bs   = (const float*)d_in[7];
    float* out = (float*)d_out;
    unsigned char* wsb = (unsigned char*)d_ws;

    hipLaunchKernelGGL(prep, dim3(193), dim3(256), 0, stream,
                       Ws, pext, cext, midx, umem, wsb);
    hipLaunchKernelGGL(fused_main, dim3(NTILES, B_), dim3(256), 0, stream,
                       img, mem, midx, bs, wsb, out);
}